// Round 2
// baseline (5184.362 us; speedup 1.0000x reference)
//
#include <hip/hip_runtime.h>

#define T_STEPS 2048
#define BATCH   256
#define HID     512
#define NG      16   // gate-slice blocks per batch group (h-cols 512/NG = 32 each)
#define NB      16   // batch groups (rows 256/NB = 16 each)
#define RING    6    // h ring slots (sentinel dataflow protocol)
#define SENT    0x3C3C3C3Cu // fp16 pair (1.0586,1.0586) — unreachable: |h|<=1.0 => halves <= 0x3C00

typedef _Float16 half8 __attribute__((ext_vector_type(8)));
typedef float f32x4 __attribute__((ext_vector_type(4)));
typedef int int4v __attribute__((ext_vector_type(4)));

__device__ __forceinline__ float sigmoid_f(float v) {
    return 1.f / (1.f + __expf(-v));
}
__device__ __forceinline__ float tanh_f(float v) {
    float a = fabsf(v);
    float e = __expf(2.f * a);
    float r = 1.f - 2.f / (e + 1.f);
    return copysignf(r, v);
}

// grid = 256 blocks (g = blockIdx&15 batch group, j = blockIdx>>4 gate slice)
// block = 256 threads = 4 waves, K-split (wave w owns k in [128w,128w+128)).
//
// Sentinel-dataflow sync (no flags, no publish barrier, no flag->data trip):
//  - h lives in a 6-slot ring; slot for step t input = t%6.
//  - Producers store h with AGENT-scope relaxed atomics (compiler emits the
//    device-scope cache encoding — coherence point = MALL, not the system/
//    host-coherent point the previous sc0+sc1 version paid for).
//  - Consumers poll their own A-fragment lines with agent-scope relaxed
//    atomic loads until all dwords != SENT — the poll IS the data load.
//  - Consumed slot (t-1)%6 is reset to SENT after the mid-step barrier (the
//    barrier proves, via this block's 4 waves having collectively observed all
//    16 peer outputs of step t-1, that every peer wave finished reading it).
//  - End-of-step s_waitcnt vmcnt(0) makes resets/stores visible before this
//    block's NEXT store is issued -> inductively visible before any peer's
//    re-poll of that slot 5 steps later. WAR on slot rewrite follows from the
//    same dataflow chain (poll success at t => peers passed barrier t-1 =>
//    their reads of older slots retired).
__global__ __launch_bounds__(256, 1) void lstm_persistent(
    const float* __restrict__ x,     // (T,B)
    const float* __restrict__ Wih,   // (4H,1)
    const float* __restrict__ Whh,   // (4H,H)
    const float* __restrict__ bih,   // (4H)
    const float* __restrict__ bhh,   // (4H)
    const float* __restrict__ Wlin,  // (1,H)
    _Float16* __restrict__ hbuf,     // [RING][B][H] fp16
    float* __restrict__ partial)     // [NG][B]
{
    const int tid  = threadIdx.x;
    const int g    = blockIdx.x & 15;   // batch group
    const int j    = blockIdx.x >> 4;   // gate slice
    const int wave = tid >> 6;          // k-slice owner: k in [128*wave, 128*wave+128)
    const int lane = tid & 63;
    const int quad = lane >> 4;
    const int ln16 = lane & 15;

    // pad 34 (even): bank = (2*row + col) % 32 -> <=2-way on writes (free),
    // b64 reads ~4-way worst. Double-buffered (t&1): lets us run ONE barrier/step.
    __shared__ float lds_part[2][4][4][16][34];

    // ---- stationary weights: fp16 MFMA B-fragments in registers ----
    // bf[gate][colhalf][ksl]: B[k][n] = Whh[gate*512 + j*32 + colhalf*16 + ln16][k],
    // k = (wave*4 + ksl)*32 + quad*8 + e
    half8 bf[4][2][4];
    #pragma unroll
    for (int gt = 0; gt < 4; ++gt) {
        #pragma unroll
        for (int ch = 0; ch < 2; ++ch) {
            const float* wr = Whh + (size_t)(gt * 512 + j * 32 + ch * 16 + ln16) * HID;
            #pragma unroll
            for (int ksl = 0; ksl < 4; ++ksl) {
                int k0 = (wave * 4 + ksl) * 32 + quad * 8;
                half8 v;
                #pragma unroll
                for (int e = 0; e < 8; ++e) v[e] = (_Float16)wr[k0 + e];
                bf[gt][ch][ksl] = v;
            }
        }
    }

    const int row_e = tid >> 4;          // epilogue row 0..15
    const int cp    = (tid & 15) * 2;    // epilogue col pair 0,2,..,30

    // per-thread epilogue constants in registers
    float wxA[4], wxB[4], bsA[4], bsB[4];
    #pragma unroll
    for (int gt = 0; gt < 4; ++gt) {
        int r0 = gt * 512 + j * 32 + cp;
        wxA[gt] = Wih[r0];
        wxB[gt] = Wih[r0 + 1];
        bsA[gt] = bih[r0] + bhh[r0];
        bsB[gt] = bih[r0 + 1] + bhh[r0 + 1];
    }

    float c0 = 0.f, c1 = 0.f;            // cell state (fp32, register-resident)
    float hl0 = 0.f, hl1 = 0.f;          // last h values (fp32)
    bool  dead = false;                  // sticky bailout

    float x_cur = x[(size_t)g * 16 + row_e];   // x for t=0

    int s_in = 0, s_out = 1, s_rst = 5;

    for (int t = 0; t < T_STEPS; ++t) {
        // ---- poll own A-fragment lines of slot s_in (the poll IS the load) ----
        // 4 lines of 16B at stride 64B -> 8x 8B agent-scope relaxed atomic loads.
        const char* hp = (const char*)hbuf
            + ((size_t)s_in * (BATCH * HID) + (size_t)(g * 16 + ln16) * HID) * 2
            + wave * 256 + quad * 16;
        unsigned long long q0, q1, q2, q3, q4, q5, q6, q7;
        {
            unsigned it = 0;
            for (;;) {
                q0 = __hip_atomic_load((const unsigned long long*)(hp +   0), __ATOMIC_RELAXED, __HIP_MEMORY_SCOPE_AGENT);
                q1 = __hip_atomic_load((const unsigned long long*)(hp +   8), __ATOMIC_RELAXED, __HIP_MEMORY_SCOPE_AGENT);
                q2 = __hip_atomic_load((const unsigned long long*)(hp +  64), __ATOMIC_RELAXED, __HIP_MEMORY_SCOPE_AGENT);
                q3 = __hip_atomic_load((const unsigned long long*)(hp +  72), __ATOMIC_RELAXED, __HIP_MEMORY_SCOPE_AGENT);
                q4 = __hip_atomic_load((const unsigned long long*)(hp + 128), __ATOMIC_RELAXED, __HIP_MEMORY_SCOPE_AGENT);
                q5 = __hip_atomic_load((const unsigned long long*)(hp + 136), __ATOMIC_RELAXED, __HIP_MEMORY_SCOPE_AGENT);
                q6 = __hip_atomic_load((const unsigned long long*)(hp + 192), __ATOMIC_RELAXED, __HIP_MEMORY_SCOPE_AGENT);
                q7 = __hip_atomic_load((const unsigned long long*)(hp + 200), __ATOMIC_RELAXED, __HIP_MEMORY_SCOPE_AGENT);
                bool ok = true;
                #define CHK(q) ok = ok && ((unsigned)(q) != SENT) && ((unsigned)((q) >> 32) != SENT)
                CHK(q0); CHK(q1); CHK(q2); CHK(q3);
                CHK(q4); CHK(q5); CHK(q6); CHK(q7);
                #undef CHK
                if (__ballot(ok) == ~0ull || dead) break;
                if (++it > 100000000u) { dead = true; break; }
            }
        }
        int4v h0 = { (int)q0, (int)(q0 >> 32), (int)q1, (int)(q1 >> 32) };
        int4v h1 = { (int)q2, (int)(q2 >> 32), (int)q3, (int)(q3 >> 32) };
        int4v h2 = { (int)q4, (int)(q4 >> 32), (int)q5, (int)(q5 >> 32) };
        int4v h3 = { (int)q6, (int)(q6 >> 32), (int)q7, (int)(q7 >> 32) };

        // prefetch x for next step (overlaps MFMA + epilogue)
        float x_next = x[(size_t)(t + 1 < T_STEPS ? t + 1 : t) * BATCH + g * 16 + row_e];

        // ---- 32 MFMAs: 4 gates x 2 col-halves x 4 k-sub-slices (partial sums) ----
        f32x4 acc[4][2];
        #pragma unroll
        for (int gt = 0; gt < 4; ++gt) {
            acc[gt][0] = (f32x4){0.f, 0.f, 0.f, 0.f};
            acc[gt][1] = (f32x4){0.f, 0.f, 0.f, 0.f};
        }
        #define KSTEP(ksl, hx) {                                                      \
            half8 af = __builtin_bit_cast(half8, hx);                                 \
            _Pragma("unroll")                                                         \
            for (int gt = 0; gt < 4; ++gt) {                                          \
                acc[gt][0] = __builtin_amdgcn_mfma_f32_16x16x32_f16(af, bf[gt][0][ksl], acc[gt][0], 0, 0, 0); \
                acc[gt][1] = __builtin_amdgcn_mfma_f32_16x16x32_f16(af, bf[gt][1][ksl], acc[gt][1], 0, 0, 0); \
            } }
        KSTEP(0, h0) KSTEP(1, h1) KSTEP(2, h2) KSTEP(3, h3)
        #undef KSTEP

        // C layout: col = ln16, row = quad*4 + r  -> per-wave partials to LDS
        const int tb = t & 1;
        #pragma unroll
        for (int gt = 0; gt < 4; ++gt) {
            #pragma unroll
            for (int r = 0; r < 4; ++r) {
                lds_part[tb][wave][gt][quad * 4 + r][ln16]      = acc[gt][0][r];
                lds_part[tb][wave][gt][quad * 4 + r][16 + ln16] = acc[gt][1][r];
            }
        }
        __syncthreads();   // the ONLY barrier per step

        // ---- reset consumed slot s_rst (own 1KB region, 1 dword/thread) ----
        {
            unsigned* radr = (unsigned*)(
                (char*)hbuf
                + ((size_t)s_rst * (BATCH * HID)
                   + (size_t)(g * 16 + row_e) * HID + j * 32 + cp) * 2);
            __hip_atomic_store(radr, SENT, __ATOMIC_RELAXED, __HIP_MEMORY_SCOPE_AGENT);
        }

        // ---- epilogue: reduce 4 wave-partials, activations, c/h update ----
        const float xin = x_cur;
        float sA[4] = {0.f, 0.f, 0.f, 0.f};
        float sB[4] = {0.f, 0.f, 0.f, 0.f};
        #pragma unroll
        for (int w = 0; w < 4; ++w) {
            #pragma unroll
            for (int gt = 0; gt < 4; ++gt) {
                float2 v = *(const float2*)&lds_part[tb][w][gt][row_e][cp];
                sA[gt] += v.x;
                sB[gt] += v.y;
            }
        }
        float hv0, hv1;
        {
            float gi = sA[0] + xin * wxA[0] + bsA[0];
            float gf = sA[1] + xin * wxA[1] + bsA[1];
            float gg = sA[2] + xin * wxA[2] + bsA[2];
            float go = sA[3] + xin * wxA[3] + bsA[3];
            float iv = sigmoid_f(gi), fv = sigmoid_f(gf), gv = tanh_f(gg), ov = sigmoid_f(go);
            c0 = fv * c0 + iv * gv;
            hv0 = ov * tanh_f(c0);
        }
        {
            float gi = sB[0] + xin * wxB[0] + bsB[0];
            float gf = sB[1] + xin * wxB[1] + bsB[1];
            float gg = sB[2] + xin * wxB[2] + bsB[2];
            float go = sB[3] + xin * wxB[3] + bsB[3];
            float iv = sigmoid_f(gi), fv = sigmoid_f(gf), gv = tanh_f(gg), ov = sigmoid_f(go);
            c1 = fv * c1 + iv * gv;
            hv1 = ov * tanh_f(c1);
        }
        hl0 = hv0; hl1 = hv1;

        // ---- store h(t+1) into slot s_out; data store IS the publish ----
        {
            _Float16 p0 = (_Float16)hv0, p1 = (_Float16)hv1;
            unsigned hbits = ((unsigned)__builtin_bit_cast(unsigned short, p1) << 16)
                           |  (unsigned)__builtin_bit_cast(unsigned short, p0);
            unsigned* sadr = (unsigned*)(
                (char*)hbuf
                + ((size_t)s_out * (BATCH * HID)
                   + (size_t)(g * 16 + row_e) * HID + j * 32 + cp) * 2);
            __hip_atomic_store(sadr, hbits, __ATOMIC_RELAXED, __HIP_MEMORY_SCOPE_AGENT);
        }
        // end-of-step drain: resets + h store acked at the coherence point
        // before next iteration's stores are issued (visibility induction);
        // overlaps consumers' detect. Also a compiler barrier (memory clobber).
        asm volatile("s_waitcnt vmcnt(0)" ::: "memory");

        x_cur = x_next;
        s_rst = s_in;
        s_in  = s_out;
        s_out = (s_out + 1 == RING) ? 0 : s_out + 1;
    }

    // ---- partial output: sum over this block's 32 h-cols per row ----
    float p = hl0 * Wlin[j * 32 + cp] + hl1 * Wlin[j * 32 + cp + 1];
    #pragma unroll
    for (int off = 8; off; off >>= 1) p += __shfl_down(p, off, 16);
    if ((tid & 15) == 0) partial[(size_t)j * BATCH + g * 16 + row_e] = p;
}

__global__ void lstm_finalize(const float* __restrict__ partial,
                              const float* __restrict__ blin,
                              float* __restrict__ out)
{
    int b = threadIdx.x;
    float s = blin[0];
    #pragma unroll
    for (int jj = 0; jj < NG; ++jj) s += partial[(size_t)jj * BATCH + b];
    out[b] = s;
}

extern "C" void kernel_launch(void* const* d_in, const int* in_sizes, int n_in,
                              void* d_out, int out_size, void* d_ws, size_t ws_size,
                              hipStream_t stream) {
    const float* x    = (const float*)d_in[0];
    const float* Wih  = (const float*)d_in[1];
    const float* Whh  = (const float*)d_in[2];
    const float* bih  = (const float*)d_in[3];
    const float* bhh  = (const float*)d_in[4];
    const float* Wlin = (const float*)d_in[5];
    const float* blin = (const float*)d_in[6];

    char* ws = (char*)d_ws;
    _Float16* hbuf    = (_Float16*)ws;                   // RING * 256KB = 1.5 MB
    float*    partial = (float*)(ws + (2 << 20));        // 16 KB

    const size_t slot_bytes = (size_t)BATCH * HID * sizeof(_Float16);  // 256 KB
    // slot 0 = zeros (h(-1)); slots 1..5 = sentinel (0x3C bytes -> 0x3C3C3C3C dwords)
    hipMemsetAsync(hbuf, 0, slot_bytes, stream);
    hipMemsetAsync((char*)hbuf + slot_bytes, 0x3C, (RING - 1) * slot_bytes, stream);

    lstm_persistent<<<dim3(256), dim3(256), 0, stream>>>(
        x, Wih, Whh, bih, bhh, Wlin, hbuf, partial);
    lstm_finalize<<<dim3(1), dim3(256), 0, stream>>>(partial, blin, (float*)d_out);
}